// Round 3
// baseline (242.105 us; speedup 1.0000x reference)
//
#include <hip/hip_runtime.h>

// LIF neuron scan over STEP=4 timesteps.
// x: [4, 64, 128, 32, 32] fp32; out same shape.
// Per element: mem = mem*0.25 + x_t; spike = mem > 0.5; mem *= (1-spike).
//
// R1 -> R2: 16-VGPR version had 1 load in flight (load->waitcnt(0)->store
// per step) = latency-bound at 3.3 TB/s effective. Now: issue all 8 loads
// (4 steps x 2 adjacent float4 granules/thread) before any use; compute +
// nontemporal-store per step as data arrives (fine-grained vmcnt).
// R2 -> R3: __builtin_nontemporal_store needs a native clang vector type,
// not HIP_vector_type — use ext_vector_type(4) float throughout.

#define DECAY 0.25f

typedef float v4f __attribute__((ext_vector_type(4)));

__device__ __forceinline__ v4f lif_step(v4f& mem, const v4f xv) {
    mem = mem * DECAY + xv;                    // leaky integrate (elementwise)
    v4f s;
    s.x = mem.x > 0.5f ? 1.f : 0.f;
    s.y = mem.y > 0.5f ? 1.f : 0.f;
    s.z = mem.z > 0.5f ? 1.f : 0.f;
    s.w = mem.w > 0.5f ? 1.f : 0.f;
    mem.x = (s.x != 0.f) ? 0.f : mem.x;        // reset where spiked
    mem.y = (s.y != 0.f) ? 0.f : mem.y;
    mem.z = (s.z != 0.f) ? 0.f : mem.z;
    mem.w = (s.w != 0.f) ? 0.f : mem.w;
    return s;
}

__global__ __launch_bounds__(256) void lif_kernel(const v4f* __restrict__ x,
                                                  v4f* __restrict__ out,
                                                  int n4) {
    int i = (blockIdx.x * blockDim.x + threadIdx.x) * 2;  // 2 granules/thread
    if (i >= n4) return;

    // Issue all 8 independent loads up front -> 8 outstanding 16B loads
    // per thread before the first waitcnt.
    v4f xa[4], xb[4];
#pragma unroll
    for (int t = 0; t < 4; ++t) {
        xa[t] = x[(size_t)t * n4 + i];
        xb[t] = x[(size_t)t * n4 + i + 1];
    }

    v4f ma = (v4f)(0.f);
    v4f mb = (v4f)(0.f);

#pragma unroll
    for (int t = 0; t < 4; ++t) {
        v4f sa = lif_step(ma, xa[t]);
        v4f sb = lif_step(mb, xb[t]);
        __builtin_nontemporal_store(sa, &out[(size_t)t * n4 + i]);
        __builtin_nontemporal_store(sb, &out[(size_t)t * n4 + i + 1]);
    }
}

extern "C" void kernel_launch(void* const* d_in, const int* in_sizes, int n_in,
                              void* d_out, int out_size, void* d_ws, size_t ws_size,
                              hipStream_t stream) {
    const float* x = (const float*)d_in[0];
    float* out = (float*)d_out;

    int n = in_sizes[0];       // 4 * 64 * 128 * 32 * 32 = 33,554,432
    int n4 = n / 16;           // per-timestep float4 granule count = 2,097,152

    int block = 256;
    int grid = (n4 / 2 + block - 1) / block;   // 4096 blocks, 2 granules/thread

    lif_kernel<<<grid, block, 0, stream>>>((const v4f*)x, (v4f*)out, n4);
}

// Round 4
// 230.503 us; speedup vs baseline: 1.0503x; 1.0503x over previous
//
#include <hip/hip_runtime.h>

// LIF neuron scan over STEP=4 timesteps.
// x: [4, 64, 128, 32, 32] fp32; out same shape.
// Per element: mem = mem*0.25 + x_t; spike = mem > 0.5; mem *= (1-spike).
//
// R1: 16 VGPR, 1 load in flight, 82 us. R3: source-hoisted loads + nt
// stores REGRESSED (91 us): scheduler sank loads (VGPR=24), nt stores
// amplified WRITE_SIZE 131->150 MB, and adjacent-granule layout halved
// per-instruction coalescing.
// R4: (a) sched_barrier(0) pins the 8-load burst above the compute
// section -> 8 outstanding 16B loads/wave, fine-grained vmcnt waits,
// store-acks never gate load waits (issued younger). (b) block owns 512
// contiguous granules, thread handles tid and tid+256 -> both loads
// fully lane-coalesced. (c) plain stores.

#define DECAY 0.25f

typedef float v4f __attribute__((ext_vector_type(4)));

__device__ __forceinline__ v4f lif_step(v4f& mem, const v4f xv) {
    mem = mem * DECAY + xv;                    // leaky integrate
    v4f s;
    s.x = mem.x > 0.5f ? 1.f : 0.f;
    s.y = mem.y > 0.5f ? 1.f : 0.f;
    s.z = mem.z > 0.5f ? 1.f : 0.f;
    s.w = mem.w > 0.5f ? 1.f : 0.f;
    mem.x = (s.x != 0.f) ? 0.f : mem.x;        // reset where spiked
    mem.y = (s.y != 0.f) ? 0.f : mem.y;
    mem.z = (s.z != 0.f) ? 0.f : mem.z;
    mem.w = (s.w != 0.f) ? 0.f : mem.w;
    return s;
}

__global__ __launch_bounds__(256) void lif_kernel(const v4f* __restrict__ x,
                                                  v4f* __restrict__ out,
                                                  int n4) {
    // Block owns 512 contiguous float4 granules; each thread takes two
    // granules 256 apart so every load/store is stride-1 across the wave.
    int base = blockIdx.x * 512 + threadIdx.x;
    int ia = base;
    int ib = base + 256;
    if (ib >= n4) return;   // exact division in practice; guard is free

    // Load burst: 8 independent 16B loads, all issued before any use.
    v4f xa[4], xb[4];
#pragma unroll
    for (int t = 0; t < 4; ++t) {
        xa[t] = x[(size_t)t * n4 + ia];
        xb[t] = x[(size_t)t * n4 + ib];
    }
    // Scheduler fence: nothing may cross. Loads above cannot be sunk
    // into the compute section -> all 8 stay in flight.
    __builtin_amdgcn_sched_barrier(0);

    v4f ma = (v4f)(0.f);
    v4f mb = (v4f)(0.f);

#pragma unroll
    for (int t = 0; t < 4; ++t) {
        v4f sa = lif_step(ma, xa[t]);
        v4f sb = lif_step(mb, xb[t]);
        out[(size_t)t * n4 + ia] = sa;
        out[(size_t)t * n4 + ib] = sb;
    }
}

extern "C" void kernel_launch(void* const* d_in, const int* in_sizes, int n_in,
                              void* d_out, int out_size, void* d_ws, size_t ws_size,
                              hipStream_t stream) {
    const float* x = (const float*)d_in[0];
    float* out = (float*)d_out;

    int n = in_sizes[0];       // 4 * 64 * 128 * 32 * 32 = 33,554,432
    int n4 = n / 16;           // per-timestep float4 granule count = 2,097,152

    int block = 256;
    int grid = (n4 + 511) / 512;   // 4096 blocks, 512 granules per block

    lif_kernel<<<grid, block, 0, stream>>>((const v4f*)x, (v4f*)out, n4);
}